// Round 6
// baseline (801.840 us; speedup 1.0000x reference)
//
#include <hip/hip_runtime.h>
#include <cstdint>
#include <cstddef>

// ---------- small helpers ----------
typedef __bf16 bf16x8 __attribute__((ext_vector_type(8)));
typedef float  f32x4  __attribute__((ext_vector_type(4)));

__device__ __forceinline__ unsigned short f2bf(float f) {
    union { float f; unsigned int u; } v; v.f = f;
    unsigned int r = v.u + 0x7fffu + ((v.u >> 16) & 1u);
    return (unsigned short)(r >> 16);
}
__device__ __forceinline__ float bf2f(unsigned short h) {
    union { unsigned int u; float f; } v; v.u = ((unsigned int)h) << 16;
    return v.f;
}

// global -> LDS direct (16B per lane). LDS dest must be wave-uniform base.
#define GLL16(g, l)                                                            \
    __builtin_amdgcn_global_load_lds(                                          \
        (__attribute__((address_space(1))) void*)(g),                          \
        (__attribute__((address_space(3))) void*)(l), 16, 0, 0)

// ---------- weight convert fp32 [K][N] -> bf16 [N][K] ----------
__global__ __launch_bounds__(256) void wt_convert(const float* __restrict__ W,
                                                  unsigned short* __restrict__ Wt,
                                                  int K, int N) {
    __shared__ float t[32][33];
    int tid = threadIdx.x;
    int tx = tid & 31, ty = tid >> 5;
    int nbn = N >> 5;
    int bk = blockIdx.x / nbn, bn = blockIdx.x % nbn;
#pragma unroll
    for (int i = 0; i < 4; ++i)
        t[ty + i * 8][tx] = W[(size_t)(bk * 32 + ty + i * 8) * N + bn * 32 + tx];
    __syncthreads();
#pragma unroll
    for (int i = 0; i < 4; ++i)
        Wt[(size_t)(bn * 32 + ty + i * 8) * K + bk * 32 + tx] = f2bf(t[tx][ty + i * 8]);
}

// ---------- LayerNorm rows of 1024 fp32 -> bf16, wave per row ----------
__global__ __launch_bounds__(256) void ln_bf16(const float* __restrict__ X,
                                               const float* __restrict__ g,
                                               const float* __restrict__ be,
                                               unsigned short* __restrict__ Y) {
    int wave = threadIdx.x >> 6, lane = threadIdx.x & 63;
    size_t row = (size_t)blockIdx.x * 4 + wave;
    const float4* xr = (const float4*)(X + row * 1024);
    float4 v[4];
    float s = 0.f, s2 = 0.f;
#pragma unroll
    for (int j = 0; j < 4; ++j) {
        v[j] = xr[j * 64 + lane];
        s  += v[j].x + v[j].y + v[j].z + v[j].w;
        s2 += v[j].x * v[j].x + v[j].y * v[j].y + v[j].z * v[j].z + v[j].w * v[j].w;
    }
#pragma unroll
    for (int off = 32; off; off >>= 1) {
        s  += __shfl_xor(s, off, 64);
        s2 += __shfl_xor(s2, off, 64);
    }
    float mu = s * (1.f / 1024.f);
    float rs = rsqrtf(s2 * (1.f / 1024.f) - mu * mu + 1e-5f);
#pragma unroll
    for (int j = 0; j < 4; ++j) {
        int col = j * 256 + lane * 4;
        float4 gg = ((const float4*)g)[j * 64 + lane];
        float4 bb = ((const float4*)be)[j * 64 + lane];
        ushort4 o;
        o.x = f2bf((v[j].x - mu) * rs * gg.x + bb.x);
        o.y = f2bf((v[j].y - mu) * rs * gg.y + bb.y);
        o.z = f2bf((v[j].z - mu) * rs * gg.z + bb.z);
        o.w = f2bf((v[j].w - mu) * rs * gg.w + bb.w);
        *(ushort4*)(Y + row * 1024 + col) = o;
    }
}

// ---------- RoPE on q (stride 1024) and k (stride 2048), IN PLACE ----------
__global__ __launch_bounds__(256) void rope_qk(unsigned short* __restrict__ q,
                                               unsigned short* __restrict__ kv,
                                               const float* __restrict__ ct,
                                               const float* __restrict__ st) {
    unsigned int idx = blockIdx.x * 256 + threadIdx.x;  // B*L*H*32 = 4194304
    int i  = idx & 31;
    int hh = (idx >> 5) & 15;
    int l  = (idx >> 9) & 2047;
    int b  = idx >> 20;
    float c1 = ct[l * 64 + i],      s1 = st[l * 64 + i];
    float c2 = ct[l * 64 + i + 32], s2 = st[l * 64 + i + 32];
    size_t row  = (size_t)b * 2048 + l;
    size_t qoff = row * 1024 + hh * 64 + i;
    float q1 = bf2f(q[qoff]), q2 = bf2f(q[qoff + 32]);
    q[qoff]      = f2bf(q1 * c1 - q2 * s1);
    q[qoff + 32] = f2bf(q2 * c2 + q1 * s2);
    size_t kin = row * 2048 + hh * 64 + i;   // K = first half of kv rows
    float k1 = bf2f(kv[kin]), k2 = bf2f(kv[kin + 32]);
    kv[kin]      = f2bf(k1 * c1 - k2 * s1);
    kv[kin + 32] = f2bf(k2 * c2 + k1 * s2);
}

// ---------- V transpose: kv[b,l, 1024+h*64+d] -> vt[b,h,d,l] ----------
__global__ __launch_bounds__(256) void vtrans(const unsigned short* __restrict__ kvraw,
                                              unsigned short* __restrict__ vt) {
    __shared__ __align__(16) unsigned short t[64][72];
    int bid = blockIdx.x;
    int lc = bid & 31, hh = (bid >> 5) & 15, b = bid >> 9;
    int tid = threadIdx.x;
    int r = tid >> 2, c0 = (tid & 3) << 4;
    const unsigned short* src =
        kvraw + ((size_t)b * 2048 + lc * 64 + r) * 2048 + 1024 + hh * 64 + c0;
    // 16 shorts (32B) per thread: rows are 64 shorts, 4 threads/row
    *(uint4*)&t[r][c0]     = *(const uint4*)src;
    *(uint4*)&t[r][c0 + 8] = *(const uint4*)(src + 8);
    __syncthreads();
    int d = tid >> 2, l0 = (tid & 3) << 4;
    union { unsigned short u[16]; uint4 v[2]; } tmp;
#pragma unroll
    for (int j = 0; j < 16; ++j) tmp.u[j] = t[l0 + j][d];
    unsigned short* dst = vt + (((size_t)(b * 16 + hh)) * 64 + d) * 2048 + lc * 64 + l0;
    *(uint4*)dst       = tmp.v[0];
    *(uint4*)(dst + 8) = tmp.v[1];
}

// ---------- GEMM: C[M,N] = A[M,K](bf16, lda=K) * Bt[N,ldb]^T(bf16) + epilogue ----------
// EPI 0: bias -> bf16 | 1: bias+gelu -> bf16 | 2: bias+resid -> fp32 | 3: resid only -> fp32
template <int EPI>
__global__ __launch_bounds__(256, 2) void gemm_bt(const unsigned short* __restrict__ A,
                                                  const unsigned short* __restrict__ Bt,
                                                  const float* __restrict__ bias,
                                                  const float* __restrict__ resid,
                                                  void* __restrict__ Cout,
                                                  int M, int N, int K, int ldb) {
    __shared__ __align__(16) unsigned short As[128][64];  // 16KB, XOR-swizzled 16B chunks
    __shared__ __align__(16) unsigned short Bs[128][64];  // 16KB

    const int tid  = threadIdx.x;
    const int wave = tid >> 6;
    const int lane = tid & 63;
    const int nbx  = N >> 7;
    const int by   = blockIdx.x / nbx;
    const int bx   = blockIdx.x % nbx;

    const int wr = wave >> 1, wc = wave & 1;  // 2x2 wave grid, 64x64 out each
    const int lrow = lane >> 3, lch = lane & 7;
    const int l15 = lane & 15, l4 = lane >> 4;

    f32x4 acc[4][4] = {};

    const size_t arow0 = (size_t)by * 128;
    const size_t brow0 = (size_t)bx * 128;
    const int nkt = K >> 6;

    for (int kt = 0; kt < nkt; ++kt) {
        __syncthreads();
        const size_t kbase = (size_t)kt * 64 + (size_t)((lch ^ lrow) * 8);
#pragma unroll
        for (int i = 0; i < 4; ++i) {
            int r = i * 32 + wave * 8 + lrow;
            GLL16(A  + (arow0 + r) * K   + kbase, &As[i * 32 + wave * 8][0]);
            GLL16(Bt + (brow0 + r) * ldb + kbase, &Bs[i * 32 + wave * 8][0]);
        }
        asm volatile("s_waitcnt vmcnt(0)" ::: "memory");
        __syncthreads();

#pragma unroll
        for (int kk = 0; kk < 2; ++kk) {
            const int csw = ((kk * 4 + l4) ^ (lane & 7)) * 8;
            bf16x8 a[4], b[4];
#pragma unroll
            for (int m = 0; m < 4; ++m)
                a[m] = *(const bf16x8*)&As[wr * 64 + m * 16 + l15][csw];
#pragma unroll
            for (int n = 0; n < 4; ++n)
                b[n] = *(const bf16x8*)&Bs[wc * 64 + n * 16 + l15][csw];
#pragma unroll
            for (int m = 0; m < 4; ++m)
#pragma unroll
                for (int n = 0; n < 4; ++n)
                    acc[m][n] = __builtin_amdgcn_mfma_f32_16x16x32_bf16(a[m], b[n], acc[m][n], 0, 0, 0);
        }
    }

    const int c0 = bx * 128 + wc * 64;
    const int r0 = by * 128 + wr * 64;
    float bv[4];
#pragma unroll
    for (int n = 0; n < 4; ++n) bv[n] = (EPI == 3) ? 0.f : bias[c0 + n * 16 + l15];
#pragma unroll
    for (int m = 0; m < 4; ++m) {
#pragma unroll
        for (int r = 0; r < 4; ++r) {
            const size_t row = (size_t)(r0 + m * 16 + l4 * 4 + r);
#pragma unroll
            for (int n = 0; n < 4; ++n) {
                const int col = c0 + n * 16 + l15;
                float v = acc[m][n][r] + bv[n];
                if (EPI == 1) v = 0.5f * v * (1.0f + erff(v * 0.70710678118654752f));
                if (EPI >= 2) {
                    v += resid[row * N + col];
                    ((float*)Cout)[row * N + col] = v;
                } else {
                    ((unsigned short*)Cout)[row * N + col] = f2bf(v);
                }
            }
        }
    }
}

// ---------- Flash attention: Q[b,l,h*64+d] (ld 1024), K in kv (ld 2048), Vt[b,h,d,l] ----------
__global__ __launch_bounds__(256, 2) void flash_attn(const unsigned short* __restrict__ Q,
                                                     const unsigned short* __restrict__ Kb,
                                                     const unsigned short* __restrict__ Vt,
                                                     unsigned short* __restrict__ O) {
    __shared__ __align__(16) unsigned short Ks[64][64];       // K tile  [key][d]  (swizzled)
    __shared__ __align__(16) unsigned short Vs[64][64];       // V^T tile [d][key] (swizzled)
    __shared__ __align__(16) unsigned short Ps[4][16][64];    // per-wave P tile   (swizzled)

    const int tid = threadIdx.x;
    const int wave = tid >> 6;
    const int lane = tid & 63;
    const int l15 = lane & 15, l4 = lane >> 4;
    const int lrow = lane >> 3, lch = lane & 7;

    const int qb = blockIdx.x & 31;
    const int hh = (blockIdx.x >> 5) & 15;
    const int b  = blockIdx.x >> 9;

    // Q fragments held in registers (wave owns 16 q rows)
    const size_t qrow = (size_t)b * 2048 + qb * 64 + wave * 16 + l15;
    bf16x8 aq[2];
#pragma unroll
    for (int kk = 0; kk < 2; ++kk)
        aq[kk] = *(const bf16x8*)&Q[qrow * 1024 + hh * 64 + kk * 32 + l4 * 8];

    f32x4 o_acc[4] = {};
    float m_run[4] = {-3e38f, -3e38f, -3e38f, -3e38f};
    float l_run[4] = {};

    const size_t kbase0 = (size_t)b * 2048;
    const size_t vbase0 = ((size_t)(b * 16 + hh)) * 64;

    for (int kv = 0; kv < 32; ++kv) {
        __syncthreads();
#pragma unroll
        for (int i = 0; i < 2; ++i) {
            int r = wave * 16 + i * 8 + lrow;
            GLL16(Kb + (kbase0 + kv * 64 + r) * 2048 + hh * 64 + (lch ^ lrow) * 8,
                  &Ks[wave * 16 + i * 8][0]);
            GLL16(Vt + (vbase0 + r) * 2048 + kv * 64 + (lch ^ lrow) * 8,
                  &Vs[wave * 16 + i * 8][0]);
        }
        asm volatile("s_waitcnt vmcnt(0)" ::: "memory");
        __syncthreads();

        // S = Q K^T  (per wave: 16 q rows x 64 keys)
        f32x4 s[4] = {};
#pragma unroll
        for (int kk = 0; kk < 2; ++kk) {
            const int csw = ((kk * 4 + l4) ^ (lane & 7)) * 8;
#pragma unroll
            for (int n = 0; n < 4; ++n) {
                bf16x8 bk = *(const bf16x8*)&Ks[n * 16 + l15][csw];
                s[n] = __builtin_amdgcn_mfma_f32_16x16x32_bf16(aq[kk], bk, s[n], 0, 0, 0);
            }
        }
#pragma unroll
        for (int n = 0; n < 4; ++n) s[n] *= 0.125f;  // 1/sqrt(64)

        // online softmax over this 64-key tile
        float al[4];
#pragma unroll
        for (int r = 0; r < 4; ++r) {
            float mxr = fmaxf(fmaxf(s[0][r], s[1][r]), fmaxf(s[2][r], s[3][r]));
            mxr = fmaxf(mxr, __shfl_xor(mxr, 1, 64));
            mxr = fmaxf(mxr, __shfl_xor(mxr, 2, 64));
            mxr = fmaxf(mxr, __shfl_xor(mxr, 4, 64));
            mxr = fmaxf(mxr, __shfl_xor(mxr, 8, 64));
            float mnew = fmaxf(m_run[r], mxr);
            al[r] = __expf(m_run[r] - mnew);
            m_run[r] = mnew;
            float sum = 0.f;
#pragma unroll
            for (int n = 0; n < 4; ++n) {
                float p = __expf(s[n][r] - mnew);
                s[n][r] = p;
                sum += p;
            }
            sum += __shfl_xor(sum, 1, 64);
            sum += __shfl_xor(sum, 2, 64);
            sum += __shfl_xor(sum, 4, 64);
            sum += __shfl_xor(sum, 8, 64);
            l_run[r] = l_run[r] * al[r] + sum;
        }

        // P -> LDS (per-wave private, swizzled), then reload as A-fragments
#pragma unroll
        for (int r = 0; r < 4; ++r) {
            int rl = l4 * 4 + r;
            int sw = (rl & 7) << 3;
#pragma unroll
            for (int n = 0; n < 4; ++n)
                Ps[wave][rl][(n * 16 + l15) ^ sw] = f2bf(s[n][r]);
        }
        asm volatile("s_waitcnt lgkmcnt(0)" ::: "memory");
        __builtin_amdgcn_sched_barrier(0);
        bf16x8 ap[2];
#pragma unroll
        for (int kk = 0; kk < 2; ++kk)
            ap[kk] = *(const bf16x8*)&Ps[wave][l15][(kk * 32 + l4 * 8) ^ ((lane & 7) << 3)];

        // rescale O then accumulate P*V
#pragma unroll
        for (int n = 0; n < 4; ++n)
#pragma unroll
            for (int r = 0; r < 4; ++r) o_acc[n][r] *= al[r];
#pragma unroll
        for (int kk = 0; kk < 2; ++kk) {
            const int csw = ((kk * 4 + l4) ^ (lane & 7)) * 8;
#pragma unroll
            for (int n = 0; n < 4; ++n) {
                bf16x8 bvv = *(const bf16x8*)&Vs[n * 16 + l15][csw];
                o_acc[n] = __builtin_amdgcn_mfma_f32_16x16x32_bf16(ap[kk], bvv, o_acc[n], 0, 0, 0);
            }
        }
    }

#pragma unroll
    for (int r = 0; r < 4; ++r) {
        float inv = 1.0f / l_run[r];
        size_t row = (size_t)b * 2048 + qb * 64 + wave * 16 + l4 * 4 + r;
#pragma unroll
        for (int n = 0; n < 4; ++n)
            O[row * 1024 + hh * 64 + n * 16 + l15] = f2bf(o_acc[n][r] * inv);
    }
}

// ---------- host ----------
extern "C" void kernel_launch(void* const* d_in, const int* in_sizes, int n_in,
                              void* d_out, int out_size, void* d_ws, size_t ws_size,
                              hipStream_t stream) {
    const float* x      = (const float*)d_in[0];
    const float* ctx    = (const float*)d_in[1];
    const float* cos_t  = (const float*)d_in[2];
    const float* sin_t  = (const float*)d_in[3];
    const float* Wq     = (const float*)d_in[4];
    const float* bq     = (const float*)d_in[5];
    const float* Wkv    = (const float*)d_in[6];
    const float* bkv    = (const float*)d_in[7];
    const float* Wo     = (const float*)d_in[8];
    const float* bo     = (const float*)d_in[9];
    const float* g_q    = (const float*)d_in[10];
    const float* be_q   = (const float*)d_in[11];
    const float* g_kv   = (const float*)d_in[12];
    const float* be_kv  = (const float*)d_in[13];
    const float* g_ffn  = (const float*)d_in[14];
    const float* be_ffn = (const float*)d_in[15];
    const float* W1     = (const float*)d_in[16];
    const float* b1     = (const float*)d_in[17];
    const float* W2     = (const float*)d_in[18];
    const float* b2     = (const float*)d_in[19];

    char* ws = (char*)d_ws;
    const size_t MB = 1024 * 1024;
    // layout, peak 104MB, sequential-reuse audited:
    unsigned short* WQT  = (unsigned short*)(ws + 0 * MB);    // 2MB  [1024][1024]
    unsigned short* WKVT = (unsigned short*)(ws + 2 * MB);    // 4MB  [2048][1024]
    unsigned short* WOT  = (unsigned short*)(ws + 6 * MB);    // 2MB
    unsigned short* W1T  = (unsigned short*)(ws + 8 * MB);    // 8MB  [4096][1024]
    unsigned short* W2T  = (unsigned short*)(ws + 16 * MB);   // 8MB  [1024][4096]
    unsigned short* XN   = (unsigned short*)(ws + 24 * MB);   // 16MB; later VT; later X2N
    unsigned short* CN   = (unsigned short*)(ws + 40 * MB);   // 16MB; later ATT
    unsigned short* Qb   = (unsigned short*)(ws + 56 * MB);   // 16MB; later part of X2
    unsigned short* KV   = (unsigned short*)(ws + 72 * MB);   // 32MB [8192][2048]; dies after flash
    unsigned short* VT   = XN;                                // 16MB [b,h,64][2048]
    float*          X2   = (float*)(ws + 56 * MB);            // 32MB fp32 (over dead Qb+KV-lower)
    unsigned short* H    = (unsigned short*)(ws + 88 * MB);   // 16MB [8192][1024] (over dead KV-upper)
    unsigned short* ATT  = CN;
    unsigned short* X2N  = XN;

    // weights -> bf16, transposed [N][K]
    wt_convert<<<(1024 / 32) * (1024 / 32), 256, 0, stream>>>(Wq,  WQT,  1024, 1024);
    wt_convert<<<(1024 / 32) * (2048 / 32), 256, 0, stream>>>(Wkv, WKVT, 1024, 2048);
    wt_convert<<<(1024 / 32) * (1024 / 32), 256, 0, stream>>>(Wo,  WOT,  1024, 1024);
    wt_convert<<<(1024 / 32) * (4096 / 32), 256, 0, stream>>>(W1,  W1T,  1024, 4096);
    wt_convert<<<(4096 / 32) * (1024 / 32), 256, 0, stream>>>(W2,  W2T,  4096, 1024);

    // layernorms
    ln_bf16<<<2048, 256, 0, stream>>>(x,   g_q,  be_q,  XN);
    ln_bf16<<<2048, 256, 0, stream>>>(ctx, g_kv, be_kv, CN);

    // projections
    gemm_bt<0><<<64 * 8,  256, 0, stream>>>(XN, WQT,  bq,  nullptr, Qb, 8192, 1024, 1024, 1024);
    gemm_bt<0><<<64 * 16, 256, 0, stream>>>(CN, WKVT, bkv, nullptr, KV, 8192, 2048, 1024, 1024);

    // rope (in place on Qb and K-half of KV) + V transpose (VT overwrites dead XN)
    rope_qk<<<16384, 256, 0, stream>>>(Qb, KV, cos_t, sin_t);
    vtrans<<<2048, 256, 0, stream>>>(KV, VT);

    // attention
    flash_attn<<<2048, 256, 0, stream>>>(Qb, KV, VT, ATT);

    // output projection + residual (fp32) — Qb/KV dead now
    gemm_bt<2><<<64 * 8, 256, 0, stream>>>(ATT, WOT, bo, x, X2, 8192, 1024, 1024, 1024);

    // FFN in 4 hidden-column chunks of 1024 (bounds workspace to 16MB for H)
    ln_bf16<<<2048, 256, 0, stream>>>(X2, g_ffn, be_ffn, X2N);
    for (int c = 0; c < 4; ++c) {
        gemm_bt<1><<<64 * 8, 256, 0, stream>>>(X2N, W1T + (size_t)c * 1024 * 1024, b1 + c * 1024,
                                               nullptr, H, 8192, 1024, 1024, 1024);
        if (c == 0)
            gemm_bt<2><<<64 * 8, 256, 0, stream>>>(H, W2T, b2, X2, d_out,
                                                   8192, 1024, 1024, 4096);
        else
            gemm_bt<3><<<64 * 8, 256, 0, stream>>>(H, W2T + c * 1024, nullptr, (const float*)d_out,
                                                   d_out, 8192, 1024, 1024, 4096);
    }
}

// Round 8
// 799.282 us; speedup vs baseline: 1.0032x; 1.0032x over previous
//
#include <hip/hip_runtime.h>
#include <cstdint>
#include <cstddef>

// ---------- small helpers ----------
typedef __bf16 bf16x8 __attribute__((ext_vector_type(8)));
typedef float  f32x4  __attribute__((ext_vector_type(4)));

__device__ __forceinline__ unsigned short f2bf(float f) {
    union { float f; unsigned int u; } v; v.f = f;
    unsigned int r = v.u + 0x7fffu + ((v.u >> 16) & 1u);
    return (unsigned short)(r >> 16);
}
__device__ __forceinline__ float bf2f(unsigned short h) {
    union { unsigned int u; float f; } v; v.u = ((unsigned int)h) << 16;
    return v.f;
}

// global -> LDS direct (16B per lane). LDS dest must be wave-uniform base.
#define GLL16(g, l)                                                            \
    __builtin_amdgcn_global_load_lds(                                          \
        (__attribute__((address_space(1))) void*)(g),                          \
        (__attribute__((address_space(3))) void*)(l), 16, 0, 0)

// ---------- weight convert fp32 [K][N] -> bf16 [N][K] ----------
__global__ __launch_bounds__(256) void wt_convert(const float* __restrict__ W,
                                                  unsigned short* __restrict__ Wt,
                                                  int K, int N) {
    __shared__ float t[32][33];
    int tid = threadIdx.x;
    int tx = tid & 31, ty = tid >> 5;
    int nbn = N >> 5;
    int bk = blockIdx.x / nbn, bn = blockIdx.x % nbn;
#pragma unroll
    for (int i = 0; i < 4; ++i)
        t[ty + i * 8][tx] = W[(size_t)(bk * 32 + ty + i * 8) * N + bn * 32 + tx];
    __syncthreads();
#pragma unroll
    for (int i = 0; i < 4; ++i)
        Wt[(size_t)(bn * 32 + ty + i * 8) * K + bk * 32 + tx] = f2bf(t[tx][ty + i * 8]);
}

// ---------- LayerNorm rows of 1024 fp32 -> bf16, wave per row ----------
__global__ __launch_bounds__(256) void ln_bf16(const float* __restrict__ X,
                                               const float* __restrict__ g,
                                               const float* __restrict__ be,
                                               unsigned short* __restrict__ Y) {
    int wave = threadIdx.x >> 6, lane = threadIdx.x & 63;
    size_t row = (size_t)blockIdx.x * 4 + wave;
    const float4* xr = (const float4*)(X + row * 1024);
    float4 v[4];
    float s = 0.f, s2 = 0.f;
#pragma unroll
    for (int j = 0; j < 4; ++j) {
        v[j] = xr[j * 64 + lane];
        s  += v[j].x + v[j].y + v[j].z + v[j].w;
        s2 += v[j].x * v[j].x + v[j].y * v[j].y + v[j].z * v[j].z + v[j].w * v[j].w;
    }
#pragma unroll
    for (int off = 32; off; off >>= 1) {
        s  += __shfl_xor(s, off, 64);
        s2 += __shfl_xor(s2, off, 64);
    }
    float mu = s * (1.f / 1024.f);
    float rs = rsqrtf(s2 * (1.f / 1024.f) - mu * mu + 1e-5f);
#pragma unroll
    for (int j = 0; j < 4; ++j) {
        int col = j * 256 + lane * 4;
        float4 gg = ((const float4*)g)[j * 64 + lane];
        float4 bb = ((const float4*)be)[j * 64 + lane];
        ushort4 o;
        o.x = f2bf((v[j].x - mu) * rs * gg.x + bb.x);
        o.y = f2bf((v[j].y - mu) * rs * gg.y + bb.y);
        o.z = f2bf((v[j].z - mu) * rs * gg.z + bb.z);
        o.w = f2bf((v[j].w - mu) * rs * gg.w + bb.w);
        *(ushort4*)(Y + row * 1024 + col) = o;
    }
}

// ---------- V transpose: kv[b,l, 1024+h*64+d] -> vt[b,h,d,l] ----------
__global__ __launch_bounds__(256) void vtrans(const unsigned short* __restrict__ kvraw,
                                              unsigned short* __restrict__ vt) {
    __shared__ __align__(16) unsigned short t[64][72];
    int bid = blockIdx.x;
    int lc = bid & 31, hh = (bid >> 5) & 15, b = bid >> 9;
    int tid = threadIdx.x;
    int r = tid >> 2, c0 = (tid & 3) << 4;
    const unsigned short* src =
        kvraw + ((size_t)b * 2048 + lc * 64 + r) * 2048 + 1024 + hh * 64 + c0;
    *(uint4*)&t[r][c0]     = *(const uint4*)src;
    *(uint4*)&t[r][c0 + 8] = *(const uint4*)(src + 8);
    __syncthreads();
    int d = tid >> 2, l0 = (tid & 3) << 4;
    union { unsigned short u[16]; uint4 v[2]; } tmp;
#pragma unroll
    for (int j = 0; j < 16; ++j) tmp.u[j] = t[l0 + j][d];
    unsigned short* dst = vt + (((size_t)(b * 16 + hh)) * 64 + d) * 2048 + lc * 64 + l0;
    *(uint4*)dst       = tmp.v[0];
    *(uint4*)(dst + 8) = tmp.v[1];
}

// ---------- GEMM: C[M,N] = A[M,K](bf16) * Bt[N,ldb]^T(bf16) + epilogue ----------
// EPI 1: bias+gelu -> bf16 | 2: bias+resid -> fp32 | 3: resid -> fp32
// EPI 4: bias+rope, *0.125 -> bf16 (Q) | 5: bias, rope if col<1024 -> bf16 (KV)
template <int EPI>
__global__ __launch_bounds__(256, 3) void gemm_bt(const unsigned short* __restrict__ A,
                                                  const unsigned short* __restrict__ Bt,
                                                  const float* __restrict__ bias,
                                                  const float* __restrict__ resid,
                                                  void* __restrict__ Cout,
                                                  int M, int N, int K, int ldb,
                                                  const float* __restrict__ ct,
                                                  const float* __restrict__ st) {
    __shared__ __align__(16) unsigned short As[128][64];  // XOR-swizzled 16B chunks
    __shared__ __align__(16) unsigned short Bs[128][64];

    const int tid  = threadIdx.x;
    const int wave = tid >> 6;
    const int lane = tid & 63;
    const int nbx  = N >> 7;
    const int by   = blockIdx.x / nbx;
    const int bx   = blockIdx.x % nbx;

    const int wr = wave >> 1, wc = wave & 1;  // 2x2 wave grid, 64x64 out each
    const int lrow = lane >> 3, lch = lane & 7;
    const int l15 = lane & 15, l4 = lane >> 4;

    f32x4 acc[4][4] = {};

    const size_t arow0 = (size_t)by * 128;
    const size_t brow0 = (size_t)bx * 128;
    const int nkt = K >> 6;

    for (int kt = 0; kt < nkt; ++kt) {
        __syncthreads();
        const size_t kbase = (size_t)kt * 64 + (size_t)((lch ^ lrow) * 8);
#pragma unroll
        for (int i = 0; i < 4; ++i) {
            int r = i * 32 + wave * 8 + lrow;
            GLL16(A  + (arow0 + r) * K   + kbase, &As[i * 32 + wave * 8][0]);
            GLL16(Bt + (brow0 + r) * ldb + kbase, &Bs[i * 32 + wave * 8][0]);
        }
        asm volatile("s_waitcnt vmcnt(0)" ::: "memory");
        __syncthreads();

#pragma unroll
        for (int kk = 0; kk < 2; ++kk) {
            const int csw = ((kk * 4 + l4) ^ (lane & 7)) * 8;
            bf16x8 a[4], b[4];
#pragma unroll
            for (int m = 0; m < 4; ++m)
                a[m] = *(const bf16x8*)&As[wr * 64 + m * 16 + l15][csw];
#pragma unroll
            for (int n = 0; n < 4; ++n)
                b[n] = *(const bf16x8*)&Bs[wc * 64 + n * 16 + l15][csw];
#pragma unroll
            for (int m = 0; m < 4; ++m)
#pragma unroll
                for (int n = 0; n < 4; ++n)
                    acc[m][n] = __builtin_amdgcn_mfma_f32_16x16x32_bf16(a[m], b[n], acc[m][n], 0, 0, 0);
        }
    }

    const int c0 = bx * 128 + wc * 64;
    const int r0 = by * 128 + wr * 64;
    float bv[4];
#pragma unroll
    for (int n = 0; n < 4; ++n) bv[n] = (EPI == 3) ? 0.f : bias[c0 + n * 16 + l15];
    const bool do_rope = (EPI == 4) || (EPI == 5 && c0 < 1024);
#pragma unroll
    for (int m = 0; m < 4; ++m) {
#pragma unroll
        for (int r = 0; r < 4; ++r) {
            const size_t row = (size_t)(r0 + m * 16 + l4 * 4 + r);
            float v[4];
#pragma unroll
            for (int n = 0; n < 4; ++n) v[n] = acc[m][n][r] + bv[n];
            if (EPI == 4 || EPI == 5) {
                if (do_rope) {
                    const int l = (int)(row & 2047);
                    float o[4];
#pragma unroll
                    for (int n = 0; n < 4; ++n) {
                        const int d = n * 16 + l15;
                        const float c = ct[l * 64 + d], sn = st[l * 64 + d];
                        o[n] = (n < 2) ? v[n] * c - v[n + 2] * sn
                                       : v[n] * c + v[n - 2] * sn;
                    }
#pragma unroll
                    for (int n = 0; n < 4; ++n) {
                        float out = (EPI == 4) ? o[n] * 0.125f : o[n];
                        ((unsigned short*)Cout)[row * N + c0 + n * 16 + l15] = f2bf(out);
                    }
                } else {
#pragma unroll
                    for (int n = 0; n < 4; ++n)
                        ((unsigned short*)Cout)[row * N + c0 + n * 16 + l15] = f2bf(v[n]);
                }
            } else {
#pragma unroll
                for (int n = 0; n < 4; ++n) {
                    const int col = c0 + n * 16 + l15;
                    float val = v[n];
                    if (EPI == 1) val = 0.5f * val * (1.0f + erff(val * 0.70710678118654752f));
                    if (EPI == 2 || EPI == 3) {
                        val += resid[row * N + col];
                        ((float*)Cout)[row * N + col] = val;
                    } else {
                        ((unsigned short*)Cout)[row * N + col] = f2bf(val);
                    }
                }
            }
        }
    }
}

// ---------- Flash attention (2-phase pipelined K/V staging) ----------
// Q[b,l,h*64+d] (ld 1024, pre-scaled by 0.125, roped), K in kv (ld 2048, roped), Vt[b,h,d,l]
__global__ __launch_bounds__(256, 2) void flash_attn(const unsigned short* __restrict__ Q,
                                                     const unsigned short* __restrict__ Kb,
                                                     const unsigned short* __restrict__ Vt,
                                                     unsigned short* __restrict__ O) {
    __shared__ __align__(16) unsigned short Ks[2][64][64];    // K tiles  [key][d]  (swizzled)
    __shared__ __align__(16) unsigned short Vs[2][64][64];    // V^T tiles [d][key] (swizzled)
    __shared__ __align__(16) unsigned short Ps[4][16][64];    // per-wave P tile    (swizzled)

    const int tid = threadIdx.x;
    const int wave = tid >> 6;
    const int lane = tid & 63;
    const int l15 = lane & 15, l4 = lane >> 4;
    const int lrow = lane >> 3, lch = lane & 7;

    const int qb = blockIdx.x & 31;
    const int hh = (blockIdx.x >> 5) & 15;
    const int b  = blockIdx.x >> 9;

    // Q fragments held in registers (wave owns 16 q rows)
    const size_t qrow = (size_t)b * 2048 + qb * 64 + wave * 16 + l15;
    bf16x8 aq[2];
#pragma unroll
    for (int kk = 0; kk < 2; ++kk)
        aq[kk] = *(const bf16x8*)&Q[qrow * 1024 + hh * 64 + kk * 32 + l4 * 8];

    f32x4 o_acc[4] = {};
    float m_run[4] = {-3e38f, -3e38f, -3e38f, -3e38f};
    float l_run[4] = {};

    const size_t kbase0 = (size_t)b * 2048;
    const size_t vbase0 = ((size_t)(b * 16 + hh)) * 64;

    auto issue_tile = [&](int kvt, int bi) {
#pragma unroll
        for (int i = 0; i < 2; ++i) {
            int rr = wave * 16 + i * 8 + lrow;
            GLL16(Kb + (kbase0 + kvt * 64 + rr) * 2048 + hh * 64 + (lch ^ lrow) * 8,
                  &Ks[bi][wave * 16 + i * 8][0]);
            GLL16(Vt + (vbase0 + rr) * 2048 + kvt * 64 + (lch ^ lrow) * 8,
                  &Vs[bi][wave * 16 + i * 8][0]);
        }
    };

    issue_tile(0, 0);
    for (int kv = 0; kv < 32; ++kv) {
        const int cur = kv & 1;
        asm volatile("s_waitcnt vmcnt(0)" ::: "memory");
        __syncthreads();   // tile kv landed for all waves; all waves done reading buf cur^1
        if (kv < 31) issue_tile(kv + 1, cur ^ 1);

        // S = Q K^T (scale pre-folded into Q)
        f32x4 s[4] = {};
#pragma unroll
        for (int kk = 0; kk < 2; ++kk) {
            const int csw = ((kk * 4 + l4) ^ (lane & 7)) * 8;
#pragma unroll
            for (int n = 0; n < 4; ++n) {
                bf16x8 bk = *(const bf16x8*)&Ks[cur][n * 16 + l15][csw];
                s[n] = __builtin_amdgcn_mfma_f32_16x16x32_bf16(aq[kk], bk, s[n], 0, 0, 0);
            }
        }

        // online softmax over this 64-key tile
        float al[4];
#pragma unroll
        for (int r = 0; r < 4; ++r) {
            float mxr = fmaxf(fmaxf(s[0][r], s[1][r]), fmaxf(s[2][r], s[3][r]));
            mxr = fmaxf(mxr, __shfl_xor(mxr, 1, 64));
            mxr = fmaxf(mxr, __shfl_xor(mxr, 2, 64));
            mxr = fmaxf(mxr, __shfl_xor(mxr, 4, 64));
            mxr = fmaxf(mxr, __shfl_xor(mxr, 8, 64));
            float mnew = fmaxf(m_run[r], mxr);
            al[r] = __expf(m_run[r] - mnew);
            m_run[r] = mnew;
            float sum = 0.f;
#pragma unroll
            for (int n = 0; n < 4; ++n) {
                float p = __expf(s[n][r] - mnew);
                s[n][r] = p;
                sum += p;
            }
            sum += __shfl_xor(sum, 1, 64);
            sum += __shfl_xor(sum, 2, 64);
            sum += __shfl_xor(sum, 4, 64);
            sum += __shfl_xor(sum, 8, 64);
            l_run[r] = l_run[r] * al[r] + sum;
        }

        // P -> LDS (per-wave private, swizzled), reload as A-fragments
#pragma unroll
        for (int r = 0; r < 4; ++r) {
            int rl = l4 * 4 + r;
            int sw = (rl & 7) << 3;
#pragma unroll
            for (int n = 0; n < 4; ++n)
                Ps[wave][rl][(n * 16 + l15) ^ sw] = f2bf(s[n][r]);
        }
        asm volatile("s_waitcnt lgkmcnt(0)" ::: "memory");
        __builtin_amdgcn_sched_barrier(0);
        bf16x8 ap[2];
#pragma unroll
        for (int kk = 0; kk < 2; ++kk)
            ap[kk] = *(const bf16x8*)&Ps[wave][l15][(kk * 32 + l4 * 8) ^ ((lane & 7) << 3)];

        // rescale O then accumulate P*V
#pragma unroll
        for (int n = 0; n < 4; ++n)
#pragma unroll
            for (int r = 0; r < 4; ++r) o_acc[n][r] *= al[r];
#pragma unroll
        for (int kk = 0; kk < 2; ++kk) {
            const int csw = ((kk * 4 + l4) ^ (lane & 7)) * 8;
#pragma unroll
            for (int n = 0; n < 4; ++n) {
                bf16x8 bvv = *(const bf16x8*)&Vs[cur][n * 16 + l15][csw];
                o_acc[n] = __builtin_amdgcn_mfma_f32_16x16x32_bf16(ap[kk], bvv, o_acc[n], 0, 0, 0);
            }
        }
    }

#pragma unroll
    for (int r = 0; r < 4; ++r) {
        float inv = 1.0f / l_run[r];
        size_t row = (size_t)b * 2048 + qb * 64 + wave * 16 + l4 * 4 + r;
#pragma unroll
        for (int n = 0; n < 4; ++n)
            O[row * 1024 + hh * 64 + n * 16 + l15] = f2bf(o_acc[n][r] * inv);
    }
}

// ---------- host ----------
extern "C" void kernel_launch(void* const* d_in, const int* in_sizes, int n_in,
                              void* d_out, int out_size, void* d_ws, size_t ws_size,
                              hipStream_t stream) {
    const float* x      = (const float*)d_in[0];
    const float* ctx    = (const float*)d_in[1];
    const float* cos_t  = (const float*)d_in[2];
    const float* sin_t  = (const float*)d_in[3];
    const float* Wq     = (const float*)d_in[4];
    const float* bq     = (const float*)d_in[5];
    const float* Wkv    = (const float*)d_in[6];
    const float* bkv    = (const float*)d_in[7];
    const float* Wo     = (const float*)d_in[8];
    const float* bo     = (const float*)d_in[9];
    const float* g_q    = (const float*)d_in[10];
    const float* be_q   = (const float*)d_in[11];
    const float* g_kv   = (const float*)d_in[12];
    const float* be_kv  = (const float*)d_in[13];
    const float* g_ffn  = (const float*)d_in[14];
    const float* be_ffn = (const float*)d_in[15];
    const float* W1     = (const float*)d_in[16];
    const float* b1     = (const float*)d_in[17];
    const float* W2     = (const float*)d_in[18];
    const float* b2     = (const float*)d_in[19];

    char* ws = (char*)d_ws;
    const size_t MB = 1024 * 1024;
    // layout, peak 104MB, sequential-reuse audited:
    unsigned short* WQT  = (unsigned short*)(ws + 0 * MB);    // 2MB  [1024][1024]
    unsigned short* WKVT = (unsigned short*)(ws + 2 * MB);    // 4MB  [2048][1024]
    unsigned short* WOT  = (unsigned short*)(ws + 6 * MB);    // 2MB
    unsigned short* W1T  = (unsigned short*)(ws + 8 * MB);    // 8MB  [4096][1024]
    unsigned short* W2T  = (unsigned short*)(ws + 16 * MB);   // 8MB  [1024][4096]
    unsigned short* XN   = (unsigned short*)(ws + 24 * MB);   // 16MB; later VT; later X2N
    unsigned short* CN   = (unsigned short*)(ws + 40 * MB);   // 16MB; later ATT
    unsigned short* Qb   = (unsigned short*)(ws + 56 * MB);   // 16MB; later part of X2
    unsigned short* KV   = (unsigned short*)(ws + 72 * MB);   // 32MB [8192][2048]; dies after flash
    unsigned short* VT   = XN;                                // 16MB [b,h,64][2048]
    float*          X2   = (float*)(ws + 56 * MB);            // 32MB fp32 (over dead Qb+KV-lower)
    unsigned short* H    = (unsigned short*)(ws + 88 * MB);   // 16MB [8192][1024] (over dead KV-upper)
    unsigned short* ATT  = CN;
    unsigned short* X2N  = XN;

    // weights -> bf16, transposed [N][K]
    wt_convert<<<(1024 / 32) * (1024 / 32), 256, 0, stream>>>(Wq,  WQT,  1024, 1024);
    wt_convert<<<(1024 / 32) * (2048 / 32), 256, 0, stream>>>(Wkv, WKVT, 1024, 2048);
    wt_convert<<<(1024 / 32) * (1024 / 32), 256, 0, stream>>>(Wo,  WOT,  1024, 1024);
    wt_convert<<<(1024 / 32) * (4096 / 32), 256, 0, stream>>>(W1,  W1T,  1024, 4096);
    wt_convert<<<(4096 / 32) * (1024 / 32), 256, 0, stream>>>(W2,  W2T,  4096, 1024);

    // layernorms
    ln_bf16<<<2048, 256, 0, stream>>>(x,   g_q,  be_q,  XN);
    ln_bf16<<<2048, 256, 0, stream>>>(ctx, g_kv, be_kv, CN);

    // projections with fused RoPE (+0.125 scale on Q)
    gemm_bt<4><<<64 * 8,  256, 0, stream>>>(XN, WQT,  bq,  nullptr, Qb, 8192, 1024, 1024, 1024,
                                            cos_t, sin_t);
    gemm_bt<5><<<64 * 16, 256, 0, stream>>>(CN, WKVT, bkv, nullptr, KV, 8192, 2048, 1024, 1024,
                                            cos_t, sin_t);

    // V transpose (VT overwrites dead XN)
    vtrans<<<2048, 256, 0, stream>>>(KV, VT);

    // attention
    flash_attn<<<2048, 256, 0, stream>>>(Qb, KV, VT, ATT);

    // output projection + residual (fp32) — Qb/KV dead now
    gemm_bt<2><<<64 * 8, 256, 0, stream>>>(ATT, WOT, bo, x, X2, 8192, 1024, 1024, 1024,
                                           nullptr, nullptr);

    // FFN in 4 hidden-column chunks of 1024 (bounds workspace to 16MB for H)
    ln_bf16<<<2048, 256, 0, stream>>>(X2, g_ffn, be_ffn, X2N);
    for (int c = 0; c < 4; ++c) {
        gemm_bt<1><<<64 * 8, 256, 0, stream>>>(X2N, W1T + (size_t)c * 1024 * 1024, b1 + c * 1024,
                                               nullptr, H, 8192, 1024, 1024, 1024,
                                               nullptr, nullptr);
        if (c == 0)
            gemm_bt<2><<<64 * 8, 256, 0, stream>>>(H, W2T, b2, X2, d_out,
                                                   8192, 1024, 1024, 4096, nullptr, nullptr);
        else
            gemm_bt<3><<<64 * 8, 256, 0, stream>>>(H, W2T + c * 1024, nullptr, (const float*)d_out,
                                                   d_out, 8192, 1024, 1024, 4096, nullptr, nullptr);
    }
}

// Round 9
// 596.988 us; speedup vs baseline: 1.3431x; 1.3389x over previous
//
#include <hip/hip_runtime.h>
#include <cstdint>
#include <cstddef>

// ---------- small helpers ----------
typedef __bf16 bf16x8 __attribute__((ext_vector_type(8)));
typedef float  f32x4  __attribute__((ext_vector_type(4)));

__device__ __forceinline__ unsigned short f2bf(float f) {
    union { float f; unsigned int u; } v; v.f = f;
    unsigned int r = v.u + 0x7fffu + ((v.u >> 16) & 1u);
    return (unsigned short)(r >> 16);
}

// packed f32x2 -> bf16x2 (RTNE), low = lo  [T12 recipe: no builtin on gfx950]
__device__ __forceinline__ unsigned int cvtpk_bf16(float lo, float hi) {
    unsigned int r;
    asm("v_cvt_pk_bf16_f32 %0, %1, %2" : "=v"(r) : "v"(lo), "v"(hi));
    return r;
}

// global -> LDS direct (16B per lane). LDS dest must be wave-uniform base.
#define GLL16(g, l)                                                            \
    __builtin_amdgcn_global_load_lds(                                          \
        (__attribute__((address_space(1))) void*)(g),                          \
        (__attribute__((address_space(3))) void*)(l), 16, 0, 0)

// ---------- weight convert fp32 [K][N] -> bf16 [N][K] ----------
__global__ __launch_bounds__(256) void wt_convert(const float* __restrict__ W,
                                                  unsigned short* __restrict__ Wt,
                                                  int K, int N) {
    __shared__ float t[32][33];
    int tid = threadIdx.x;
    int tx = tid & 31, ty = tid >> 5;
    int nbn = N >> 5;
    int bk = blockIdx.x / nbn, bn = blockIdx.x % nbn;
#pragma unroll
    for (int i = 0; i < 4; ++i)
        t[ty + i * 8][tx] = W[(size_t)(bk * 32 + ty + i * 8) * N + bn * 32 + tx];
    __syncthreads();
#pragma unroll
    for (int i = 0; i < 4; ++i)
        Wt[(size_t)(bn * 32 + ty + i * 8) * K + bk * 32 + tx] = f2bf(t[tx][ty + i * 8]);
}

// ---------- LayerNorm rows of 1024 fp32 -> bf16, wave per row ----------
__global__ __launch_bounds__(256) void ln_bf16(const float* __restrict__ X,
                                               const float* __restrict__ g,
                                               const float* __restrict__ be,
                                               unsigned short* __restrict__ Y) {
    int wave = threadIdx.x >> 6, lane = threadIdx.x & 63;
    size_t row = (size_t)blockIdx.x * 4 + wave;
    const float4* xr = (const float4*)(X + row * 1024);
    float4 v[4];
    float s = 0.f, s2 = 0.f;
#pragma unroll
    for (int j = 0; j < 4; ++j) {
        v[j] = xr[j * 64 + lane];
        s  += v[j].x + v[j].y + v[j].z + v[j].w;
        s2 += v[j].x * v[j].x + v[j].y * v[j].y + v[j].z * v[j].z + v[j].w * v[j].w;
    }
#pragma unroll
    for (int off = 32; off; off >>= 1) {
        s  += __shfl_xor(s, off, 64);
        s2 += __shfl_xor(s2, off, 64);
    }
    float mu = s * (1.f / 1024.f);
    float rs = rsqrtf(s2 * (1.f / 1024.f) - mu * mu + 1e-5f);
#pragma unroll
    for (int j = 0; j < 4; ++j) {
        int col = j * 256 + lane * 4;
        float4 gg = ((const float4*)g)[j * 64 + lane];
        float4 bb = ((const float4*)be)[j * 64 + lane];
        ushort4 o;
        o.x = f2bf((v[j].x - mu) * rs * gg.x + bb.x);
        o.y = f2bf((v[j].y - mu) * rs * gg.y + bb.y);
        o.z = f2bf((v[j].z - mu) * rs * gg.z + bb.z);
        o.w = f2bf((v[j].w - mu) * rs * gg.w + bb.w);
        *(ushort4*)(Y + row * 1024 + col) = o;
    }
}

// ---------- V transpose: kv[b,l, 1024+h*64+d] -> vt[b,h,d,l] ----------
__global__ __launch_bounds__(256) void vtrans(const unsigned short* __restrict__ kvraw,
                                              unsigned short* __restrict__ vt) {
    __shared__ __align__(16) unsigned short t[64][72];
    int bid = blockIdx.x;
    int lc = bid & 31, hh = (bid >> 5) & 15, b = bid >> 9;
    int tid = threadIdx.x;
    int r = tid >> 2, c0 = (tid & 3) << 4;
    const unsigned short* src =
        kvraw + ((size_t)b * 2048 + lc * 64 + r) * 2048 + 1024 + hh * 64 + c0;
    *(uint4*)&t[r][c0]     = *(const uint4*)src;
    *(uint4*)&t[r][c0 + 8] = *(const uint4*)(src + 8);
    __syncthreads();
    int d = tid >> 2, l0 = (tid & 3) << 4;
    union { unsigned short u[16]; uint4 v[2]; } tmp;
#pragma unroll
    for (int j = 0; j < 16; ++j) tmp.u[j] = t[l0 + j][d];
    unsigned short* dst = vt + (((size_t)(b * 16 + hh)) * 64 + d) * 2048 + lc * 64 + l0;
    *(uint4*)dst       = tmp.v[0];
    *(uint4*)(dst + 8) = tmp.v[1];
}

// ---------- GEMM: C[M,N] = A[M,K](bf16) * Bt[N,ldb]^T(bf16) + epilogue ----------
// EPI 1: bias+gelu -> bf16 | 2: bias+resid -> fp32 | 3: resid -> fp32
// EPI 4: bias+rope, *0.125 -> bf16 (Q) | 5: bias, rope if col<1024 -> bf16 (KV)
template <int EPI>
__global__ __launch_bounds__(256, 3) void gemm_bt(const unsigned short* __restrict__ A,
                                                  const unsigned short* __restrict__ Bt,
                                                  const float* __restrict__ bias,
                                                  const float* __restrict__ resid,
                                                  void* __restrict__ Cout,
                                                  int M, int N, int K, int ldb,
                                                  const float* __restrict__ ct,
                                                  const float* __restrict__ st) {
    __shared__ __align__(16) unsigned short As[128][64];  // XOR-swizzled 16B chunks
    __shared__ __align__(16) unsigned short Bs[128][64];

    const int tid  = threadIdx.x;
    const int wave = tid >> 6;
    const int lane = tid & 63;
    const int nbx  = N >> 7;
    const int by   = blockIdx.x / nbx;
    const int bx   = blockIdx.x % nbx;

    const int wr = wave >> 1, wc = wave & 1;  // 2x2 wave grid, 64x64 out each
    const int lrow = lane >> 3, lch = lane & 7;
    const int l15 = lane & 15, l4 = lane >> 4;

    f32x4 acc[4][4] = {};

    const size_t arow0 = (size_t)by * 128;
    const size_t brow0 = (size_t)bx * 128;
    const int nkt = K >> 6;

    for (int kt = 0; kt < nkt; ++kt) {
        __syncthreads();
        const size_t kbase = (size_t)kt * 64 + (size_t)((lch ^ lrow) * 8);
#pragma unroll
        for (int i = 0; i < 4; ++i) {
            int r = i * 32 + wave * 8 + lrow;
            GLL16(A  + (arow0 + r) * K   + kbase, &As[i * 32 + wave * 8][0]);
            GLL16(Bt + (brow0 + r) * ldb + kbase, &Bs[i * 32 + wave * 8][0]);
        }
        asm volatile("s_waitcnt vmcnt(0)" ::: "memory");
        __syncthreads();

#pragma unroll
        for (int kk = 0; kk < 2; ++kk) {
            const int csw = ((kk * 4 + l4) ^ (lane & 7)) * 8;
            bf16x8 a[4], b[4];
#pragma unroll
            for (int m = 0; m < 4; ++m)
                a[m] = *(const bf16x8*)&As[wr * 64 + m * 16 + l15][csw];
#pragma unroll
            for (int n = 0; n < 4; ++n)
                b[n] = *(const bf16x8*)&Bs[wc * 64 + n * 16 + l15][csw];
#pragma unroll
            for (int m = 0; m < 4; ++m)
#pragma unroll
                for (int n = 0; n < 4; ++n)
                    acc[m][n] = __builtin_amdgcn_mfma_f32_16x16x32_bf16(a[m], b[n], acc[m][n], 0, 0, 0);
        }
    }

    const int c0 = bx * 128 + wc * 64;
    const int r0 = by * 128 + wr * 64;
    float bv[4];
#pragma unroll
    for (int n = 0; n < 4; ++n) bv[n] = (EPI == 3) ? 0.f : bias[c0 + n * 16 + l15];
    const bool do_rope = (EPI == 4) || (EPI == 5 && c0 < 1024);
#pragma unroll
    for (int m = 0; m < 4; ++m) {
#pragma unroll
        for (int r = 0; r < 4; ++r) {
            const size_t row = (size_t)(r0 + m * 16 + l4 * 4 + r);
            float v[4];
#pragma unroll
            for (int n = 0; n < 4; ++n) v[n] = acc[m][n][r] + bv[n];
            if (EPI == 4 || EPI == 5) {
                if (do_rope) {
                    const int l = (int)(row & 2047);
                    float o[4];
#pragma unroll
                    for (int n = 0; n < 4; ++n) {
                        const int d = n * 16 + l15;
                        const float c = ct[l * 64 + d], sn = st[l * 64 + d];
                        o[n] = (n < 2) ? v[n] * c - v[n + 2] * sn
                                       : v[n] * c + v[n - 2] * sn;
                    }
#pragma unroll
                    for (int n = 0; n < 4; ++n) {
                        float out = (EPI == 4) ? o[n] * 0.125f : o[n];
                        ((unsigned short*)Cout)[row * N + c0 + n * 16 + l15] = f2bf(out);
                    }
                } else {
#pragma unroll
                    for (int n = 0; n < 4; ++n)
                        ((unsigned short*)Cout)[row * N + c0 + n * 16 + l15] = f2bf(v[n]);
                }
            } else {
#pragma unroll
                for (int n = 0; n < 4; ++n) {
                    const int col = c0 + n * 16 + l15;
                    float val = v[n];
                    if (EPI == 1) val = 0.5f * val * (1.0f + erff(val * 0.70710678118654752f));
                    if (EPI == 2 || EPI == 3) {
                        val += resid[row * N + col];
                        ((float*)Cout)[row * N + col] = val;
                    } else {
                        ((unsigned short*)Cout)[row * N + col] = f2bf(val);
                    }
                }
            }
        }
    }
}

// ---------- Flash attention, swapped-operand layout ----------
// S^T = mfma(K, Q): lane holds q=l15 (col), keys n*16+l4*4+r (rows) -> scalar
// per-lane softmax state. PV = mfma(V^T, P^T) -> O^T. Q pre-scaled by 0.125.
__global__ __launch_bounds__(256, 4) void flash_attn(const unsigned short* __restrict__ Q,
                                                     const unsigned short* __restrict__ Kb,
                                                     const unsigned short* __restrict__ Vt,
                                                     unsigned short* __restrict__ O) {
    __shared__ __align__(16) unsigned short Ks[2][64][64];  // K tiles  [key][d] (swizzled)
    __shared__ __align__(16) unsigned short Vs[2][64][64];  // V^T tiles [d][key] (swizzled)
    __shared__ __align__(16) unsigned int   Pd[4][32][16];  // per-wave packed P^T pairs

    const int tid = threadIdx.x;
    const int wave = tid >> 6;
    const int lane = tid & 63;
    const int l15 = lane & 15, l4 = lane >> 4;
    const int lrow = lane >> 3, lch = lane & 7;

    const int qb = blockIdx.x & 31;
    const int hh = (blockIdx.x >> 5) & 15;
    const int b  = blockIdx.x >> 9;

    // Q fragments (B-operand): lane j=l15 -> q-row wave*16+l15, k-chunk l4*8
    const size_t qrow = (size_t)b * 2048 + qb * 64 + wave * 16 + l15;
    bf16x8 aq[2];
#pragma unroll
    for (int kk = 0; kk < 2; ++kk)
        aq[kk] = *(const bf16x8*)&Q[qrow * 1024 + hh * 64 + kk * 32 + l4 * 8];

    f32x4 o_acc[4] = {};
    float m_run = -3e38f, l_run = 0.f;

    const size_t kbase0 = (size_t)b * 2048;
    const size_t vbase0 = ((size_t)(b * 16 + hh)) * 64;

    auto issue_tile = [&](int kvt, int bi) {
#pragma unroll
        for (int i = 0; i < 2; ++i) {
            int rr = wave * 16 + i * 8 + lrow;
            GLL16(Kb + (kbase0 + kvt * 64 + rr) * 2048 + hh * 64 + (lch ^ lrow) * 8,
                  &Ks[bi][wave * 16 + i * 8][0]);
            GLL16(Vt + (vbase0 + rr) * 2048 + kvt * 64 + (lch ^ lrow) * 8,
                  &Vs[bi][wave * 16 + i * 8][0]);
        }
    };

    issue_tile(0, 0);
    for (int kv = 0; kv < 32; ++kv) {
        const int cur = kv & 1;
        asm volatile("s_waitcnt vmcnt(0)" ::: "memory");
        __syncthreads();
        if (kv < 31) issue_tile(kv + 1, cur ^ 1);

        // S^T = K Q^T  (A=K rows=key, B=Q cols=q)
        f32x4 s[4] = {};
        __builtin_amdgcn_s_setprio(1);
#pragma unroll
        for (int kk = 0; kk < 2; ++kk) {
            const int csw = ((kk * 4 + l4) ^ (lane & 7)) * 8;
#pragma unroll
            for (int n = 0; n < 4; ++n) {
                bf16x8 bk = *(const bf16x8*)&Ks[cur][n * 16 + l15][csw];
                s[n] = __builtin_amdgcn_mfma_f32_16x16x32_bf16(bk, aq[kk], s[n], 0, 0, 0);
            }
        }
        __builtin_amdgcn_s_setprio(0);

        // scalar per-lane online softmax for q = l15 (keys spread over l4-groups)
        float mx = s[0][0];
#pragma unroll
        for (int n = 0; n < 4; ++n)
#pragma unroll
            for (int r = 0; r < 4; ++r)
                if (n | r) mx = fmaxf(mx, s[n][r]);
        mx = fmaxf(mx, __shfl_xor(mx, 16, 64));
        mx = fmaxf(mx, __shfl_xor(mx, 32, 64));
        float mnew = fmaxf(m_run, mx);
        float al = __expf(m_run - mnew);
        m_run = mnew;
        float sum = 0.f;
#pragma unroll
        for (int n = 0; n < 4; ++n)
#pragma unroll
            for (int r = 0; r < 4; ++r) {
                float p = __expf(s[n][r] - mnew);
                s[n][r] = p;
                sum += p;
            }
        sum += __shfl_xor(sum, 16, 64);
        sum += __shfl_xor(sum, 32, 64);
        l_run = l_run * al + sum;

        // pack P^T pairs -> per-wave LDS transpose (key-pair major, q col)
#pragma unroll
        for (int n = 0; n < 4; ++n)
#pragma unroll
            for (int h = 0; h < 2; ++h)
                Pd[wave][n * 8 + l4 * 2 + h][l15] = cvtpk_bf16(s[n][2 * h], s[n][2 * h + 1]);
        asm volatile("s_waitcnt lgkmcnt(0)" ::: "memory");
        __builtin_amdgcn_sched_barrier(0);

        // rescale O^T by al (scalar: all of lane's output is q=l15)
#pragma unroll
        for (int n = 0; n < 4; ++n)
#pragma unroll
            for (int r = 0; r < 4; ++r) o_acc[n][r] *= al;

        // PV: O^T += V^T * P^T   (A=V^T rows=d, B=P^T cols=q)
        __builtin_amdgcn_s_setprio(1);
#pragma unroll
        for (int kk = 0; kk < 2; ++kk) {
            union { unsigned int u[4]; bf16x8 v; } bp;
#pragma unroll
            for (int w = 0; w < 4; ++w)
                bp.u[w] = Pd[wave][kk * 16 + l4 * 4 + w][l15];
            const int csw = ((kk * 4 + l4) ^ (lane & 7)) * 8;
#pragma unroll
            for (int n = 0; n < 4; ++n) {
                bf16x8 av = *(const bf16x8*)&Vs[cur][n * 16 + l15][csw];
                o_acc[n] = __builtin_amdgcn_mfma_f32_16x16x32_bf16(av, bp.v, o_acc[n], 0, 0, 0);
            }
        }
        __builtin_amdgcn_s_setprio(0);
    }

    const float inv = 1.0f / l_run;
    const size_t orow = (size_t)b * 2048 + qb * 64 + wave * 16 + l15;
#pragma unroll
    for (int n = 0; n < 4; ++n) {
        ushort4 o;
        o.x = f2bf(o_acc[n][0] * inv);
        o.y = f2bf(o_acc[n][1] * inv);
        o.z = f2bf(o_acc[n][2] * inv);
        o.w = f2bf(o_acc[n][3] * inv);
        *(ushort4*)&O[orow * 1024 + hh * 64 + n * 16 + l4 * 4] = o;
    }
}

// ---------- host ----------
extern "C" void kernel_launch(void* const* d_in, const int* in_sizes, int n_in,
                              void* d_out, int out_size, void* d_ws, size_t ws_size,
                              hipStream_t stream) {
    const float* x      = (const float*)d_in[0];
    const float* ctx    = (const float*)d_in[1];
    const float* cos_t  = (const float*)d_in[2];
    const float* sin_t  = (const float*)d_in[3];
    const float* Wq     = (const float*)d_in[4];
    const float* bq     = (const float*)d_in[5];
    const float* Wkv    = (const float*)d_in[6];
    const float* bkv    = (const float*)d_in[7];
    const float* Wo     = (const float*)d_in[8];
    const float* bo     = (const float*)d_in[9];
    const float* g_q    = (const float*)d_in[10];
    const float* be_q   = (const float*)d_in[11];
    const float* g_kv   = (const float*)d_in[12];
    const float* be_kv  = (const float*)d_in[13];
    const float* g_ffn  = (const float*)d_in[14];
    const float* be_ffn = (const float*)d_in[15];
    const float* W1     = (const float*)d_in[16];
    const float* b1     = (const float*)d_in[17];
    const float* W2     = (const float*)d_in[18];
    const float* b2     = (const float*)d_in[19];

    char* ws = (char*)d_ws;
    const size_t MB = 1024 * 1024;
    // layout, peak 104MB (152MB when big-ws FFN path), sequential-reuse audited:
    unsigned short* WQT  = (unsigned short*)(ws + 0 * MB);    // 2MB  [1024][1024]
    unsigned short* WKVT = (unsigned short*)(ws + 2 * MB);    // 4MB  [2048][1024]
    unsigned short* WOT  = (unsigned short*)(ws + 6 * MB);    // 2MB
    unsigned short* W1T  = (unsigned short*)(ws + 8 * MB);    // 8MB  [4096][1024]
    unsigned short* W2T  = (unsigned short*)(ws + 16 * MB);   // 8MB  [1024][4096]
    unsigned short* XN   = (unsigned short*)(ws + 24 * MB);   // 16MB; later VT; later X2N
    unsigned short* CN   = (unsigned short*)(ws + 40 * MB);   // 16MB; later ATT
    unsigned short* Qb   = (unsigned short*)(ws + 56 * MB);   // 16MB; later part of X2
    unsigned short* KV   = (unsigned short*)(ws + 72 * MB);   // 32MB [8192][2048]; dies after flash
    unsigned short* VT   = XN;                                // 16MB [b,h,64][2048]
    float*          X2   = (float*)(ws + 56 * MB);            // 32MB fp32 (over dead Qb+KV-lower)
    unsigned short* H    = (unsigned short*)(ws + 88 * MB);   // 16MB chunked / 64MB big
    unsigned short* ATT  = CN;
    unsigned short* X2N  = XN;

    // weights -> bf16, transposed [N][K]
    wt_convert<<<(1024 / 32) * (1024 / 32), 256, 0, stream>>>(Wq,  WQT,  1024, 1024);
    wt_convert<<<(1024 / 32) * (2048 / 32), 256, 0, stream>>>(Wkv, WKVT, 1024, 2048);
    wt_convert<<<(1024 / 32) * (1024 / 32), 256, 0, stream>>>(Wo,  WOT,  1024, 1024);
    wt_convert<<<(1024 / 32) * (4096 / 32), 256, 0, stream>>>(W1,  W1T,  1024, 4096);
    wt_convert<<<(4096 / 32) * (1024 / 32), 256, 0, stream>>>(W2,  W2T,  4096, 1024);

    // layernorms
    ln_bf16<<<2048, 256, 0, stream>>>(x,   g_q,  be_q,  XN);
    ln_bf16<<<2048, 256, 0, stream>>>(ctx, g_kv, be_kv, CN);

    // projections with fused RoPE (+0.125 scale on Q)
    gemm_bt<4><<<64 * 8,  256, 0, stream>>>(XN, WQT,  bq,  nullptr, Qb, 8192, 1024, 1024, 1024,
                                            cos_t, sin_t);
    gemm_bt<5><<<64 * 16, 256, 0, stream>>>(CN, WKVT, bkv, nullptr, KV, 8192, 2048, 1024, 1024,
                                            cos_t, sin_t);

    // V transpose (VT overwrites dead XN)
    vtrans<<<2048, 256, 0, stream>>>(KV, VT);

    // attention
    flash_attn<<<2048, 256, 0, stream>>>(Qb, KV, VT, ATT);

    // output projection + residual (fp32) — Qb/KV dead now
    gemm_bt<2><<<64 * 8, 256, 0, stream>>>(ATT, WOT, bo, x, X2, 8192, 1024, 1024, 1024,
                                           nullptr, nullptr);

    // FFN
    ln_bf16<<<2048, 256, 0, stream>>>(X2, g_ffn, be_ffn, X2N);
    if (ws_size >= (size_t)152 * MB) {
        // single-shot: H = [8192][4096] bf16 @ 88..152MB (over dead KV/VT tail)
        gemm_bt<1><<<64 * 32, 256, 0, stream>>>(X2N, W1T, b1, nullptr, H,
                                                8192, 4096, 1024, 1024, nullptr, nullptr);
        gemm_bt<2><<<64 * 8,  256, 0, stream>>>(H, W2T, b2, X2, d_out,
                                                8192, 1024, 4096, 4096, nullptr, nullptr);
    } else {
        // fallback: 4 hidden-column chunks of 1024 (H 16MB @ 88MB)
        for (int c = 0; c < 4; ++c) {
            gemm_bt<1><<<64 * 8, 256, 0, stream>>>(X2N, W1T + (size_t)c * 1024 * 1024,
                                                   b1 + c * 1024, nullptr, H,
                                                   8192, 1024, 1024, 1024, nullptr, nullptr);
            if (c == 0)
                gemm_bt<2><<<64 * 8, 256, 0, stream>>>(H, W2T, b2, X2, d_out,
                                                       8192, 1024, 1024, 4096, nullptr, nullptr);
            else
                gemm_bt<3><<<64 * 8, 256, 0, stream>>>(H, W2T + c * 1024, nullptr,
                                                       (const float*)d_out, d_out,
                                                       8192, 1024, 1024, 4096, nullptr, nullptr);
        }
    }
}